// Round 6
// baseline (682.588 us; speedup 1.0000x reference)
//
#include <hip/hip_runtime.h>
#include <hip/hip_bf16.h>

#define B_ 8
#define L_ 2048
#define D_ 128
#define BL_ (B_ * L_)
#define DELTA2 0.016f   // 2*delta; rigorous bf16 dot bound is 0.008, 2x margin
#define QW 1280         // per-wave queue capacity (>= 256 + worst-case 1024/tile)

typedef __attribute__((ext_vector_type(8))) short bf16x8;
typedef __attribute__((ext_vector_type(4))) float f32x4;

// ---------------- K1: normalize + bf16 cast ----------------
__global__ void k_norm(const float* __restrict__ ctx,
                       float* __restrict__ cn, float* __restrict__ en,
                       ushort* __restrict__ cnb, ushort* __restrict__ enb) {
    int wid  = blockIdx.x * 4 + (threadIdx.x >> 6);
    int lane = threadIdx.x & 63;
    int b   = wid >> 12;
    int rem = wid & 4095;
    int c   = rem >> 11;
    int l   = rem & 2047;

    const float* src = ctx + (size_t)wid * D_;
    float2 v = ((const float2*)src)[lane];
    float ss = v.x * v.x + v.y * v.y;
    #pragma unroll
    for (int off = 32; off; off >>= 1) ss += __shfl_down(ss, off, 64);
    ss = __shfl(ss, 0, 64);
    float n = fmaxf(sqrtf(ss), 1e-8f);
    float ox = v.x / n, oy = v.y / n;

    size_t ro = (size_t)(b * L_ + l) * D_;
    float* dst = (c == 0 ? cn : en) + ro;
    ((float2*)dst)[lane] = make_float2(ox, oy);

    __hip_bfloat16 hx = __float2bfloat16(ox), hy = __float2bfloat16(oy);
    ushort ux = *(ushort*)&hx, uy = *(ushort*)&hy;
    ushort* dstb = (c == 0 ? cnb : enb) + ro;
    ((ushort2*)dstb)[lane] = make_ushort2(ux, uy);
}

// wave-cooperative exact double dot for queued candidates (wave-private state)
__device__ __forceinline__ void drainq(const int2* qw, int lo, int hi, int lane,
                                       const float* __restrict__ cn,
                                       const float* __restrict__ en,
                                       int b, int row0,
                                       unsigned long long* bw,
                                       const float* rowth, bool filt) {
    for (int e = lo; e < hi; ++e) {
        int2 ent = qw[e];
        int rc = ent.y;
        int rowloc = rc >> 11, col = rc & 2047;
        if (filt && __int_as_float(ent.x) < rowth[rowloc]) continue;
        const float* ar = cn + ((size_t)(b * L_) + row0 + rowloc) * D_;
        const float* br = en + ((size_t)(b * L_) + col) * D_;
        float2 x = ((const float2*)ar)[lane];
        float2 y = ((const float2*)br)[lane];
        double s = (double)x.x * y.x + (double)x.y * y.y;
        #pragma unroll
        for (int off = 32; off; off >>= 1) s += __shfl_down(s, off, 64);
        if (lane == 0) {
            unsigned long long ub = (unsigned long long)__double_as_longlong(s);
            ub = (ub & 0x8000000000000000ULL) ? ~ub : (ub | 0x8000000000000000ULL);
            ub = (ub & ~0x7FFULL) | (unsigned long long)(2047 - col);
            if (ub > bw[rowloc]) bw[rowloc] = ub;
        }
    }
}

// ---------------- K2: fused sim + online argmax + exact repair, SINGLE B-pass ----------------
// grid 256: b = blk&7 (XCD), rb = blk>>3. Block = 64 rows x 2048 cols, 8 waves;
// wave w owns cols [w*256,(w+1)*256) = 4 tiles of 64x64, pipelined over 16 (t,kc) stages.
__global__ __launch_bounds__(512) void k_sim(const ushort* __restrict__ cnb,
                                             const ushort* __restrict__ enb,
                                             const float* __restrict__ cn,
                                             const float* __restrict__ en,
                                             int* __restrict__ finalidx) {
    __shared__ int2 qbuf[8][QW];                    // 80 KB
    __shared__ unsigned long long bestw[8][64];     // 4 KB
    __shared__ float wrowmax[8][64];                // 2 KB
    __shared__ float rowth[64];
    __shared__ int qn[8];

    int bid = blockIdx.x;
    int b = bid & 7, rb = bid >> 3;
    int row0 = rb * 64;
    int tid = threadIdx.x;
    int wave = tid >> 6, lane = tid & 63;
    int m = lane & 15, q = lane >> 4;

    if (lane == 0) qn[wave] = 0;
    bestw[wave][lane] = 0ULL;

    const ushort* Ab  = cnb + ((size_t)(b * L_) + row0) * D_;
    const ushort* Bb0 = enb + (size_t)(b * L_) * D_;
    int colw = wave * 256;

    bf16x8 Areg[16];
    #pragma unroll
    for (int rt = 0; rt < 4; ++rt)
        #pragma unroll
        for (int kc = 0; kc < 4; ++kc)
            Areg[rt * 4 + kc] = *(const bf16x8*)(Ab + (size_t)(rt * 16 + m) * D_ + kc * 32 + q * 8);

    float rm[16];
    int   ri[16];
    #pragma unroll
    for (int s = 0; s < 16; ++s) { rm[s] = -3.0e38f; ri[s] = 0; }

    f32x4 acc[4][4];
    bf16x8 Bbuf[2][4];

    // stage s = (t<<2)|kc ; prologue load stage 0
    #pragma unroll
    for (int ct = 0; ct < 4; ++ct)
        Bbuf[0][ct] = *(const bf16x8*)(Bb0 + (size_t)(colw + ct * 16 + m) * D_ + q * 8);

    #pragma unroll
    for (int stage = 0; stage < 16; ++stage) {
        const int t = stage >> 2, kc = stage & 3;
        // prefetch next stage
        if (stage + 1 < 16) {
            const int nt = (stage + 1) >> 2, nkc = (stage + 1) & 3;
            #pragma unroll
            for (int ct = 0; ct < 4; ++ct)
                Bbuf[(stage + 1) & 1][ct] = *(const bf16x8*)(
                    Bb0 + (size_t)(colw + nt * 64 + ct * 16 + m) * D_ + nkc * 32 + q * 8);
        }
        if (kc == 0) {
            #pragma unroll
            for (int rt = 0; rt < 4; ++rt)
                #pragma unroll
                for (int ct = 0; ct < 4; ++ct) acc[rt][ct] = (f32x4){0.f, 0.f, 0.f, 0.f};
        }
        #pragma unroll
        for (int rt = 0; rt < 4; ++rt)
            #pragma unroll
            for (int ct = 0; ct < 4; ++ct)
                acc[rt][ct] = __builtin_amdgcn_mfma_f32_16x16x32_bf16(
                    Areg[rt * 4 + kc], Bbuf[stage & 1][ct], acc[rt][ct], 0, 0, 0);
        if (kc == 3) {
            int col0 = colw + t * 64;
            // wave-local overflow drain (unfiltered; expected never for random data)
            if (qn[wave] > QW - 1024) {
                int hi = qn[wave]; if (hi > QW) hi = QW;
                drainq(qbuf[wave], 0, hi, lane, cn, en, b, row0, bestw[wave], rowth, false);
                if (lane == 0) qn[wave] = 0;
            }
            #pragma unroll
            for (int rt = 0; rt < 4; ++rt)
                #pragma unroll
                for (int reg = 0; reg < 4; ++reg) {
                    int s = rt * 4 + reg;
                    float rmv = rm[s]; int riv = ri[s];
                    int rowloc = rt * 16 + q * 4 + reg;
                    #pragma unroll
                    for (int ct = 0; ct < 4; ++ct) {
                        float v = acc[rt][ct][reg];
                        int   c = col0 + ct * 16 + m;
                        bool nm = v > rmv;
                        float newmax   = nm ? v : rmv;
                        float loser    = nm ? rmv : v;
                        int   loserIdx = nm ? riv : c;
                        if (nm) { rmv = v; riv = c; }
                        if (loser >= newmax - DELTA2) {
                            int pos = atomicAdd(&qn[wave], 1);
                            if (pos < QW)
                                qbuf[wave][pos] = make_int2(__float_as_int(loser),
                                                            (rowloc << 11) | loserIdx);
                        }
                    }
                    rm[s] = rmv; ri[s] = riv;
                }
        }
    }

    // block row-max -> threshold
    #pragma unroll
    for (int rt = 0; rt < 4; ++rt)
        #pragma unroll
        for (int reg = 0; reg < 4; ++reg) {
            int s = rt * 4 + reg;
            float v = rm[s];
            v = fmaxf(v, __shfl_xor(v, 1, 64));
            v = fmaxf(v, __shfl_xor(v, 2, 64));
            v = fmaxf(v, __shfl_xor(v, 4, 64));
            v = fmaxf(v, __shfl_xor(v, 8, 64));
            if (m == 0) wrowmax[wave][rt * 16 + q * 4 + reg] = v;
        }
    __syncthreads();
    if (tid < 64) {
        float rmx = wrowmax[0][tid];
        #pragma unroll
        for (int w = 1; w < 8; ++w) rmx = fmaxf(rmx, wrowmax[w][tid]);
        rowth[tid] = rmx - DELTA2;
    }
    __syncthreads();

    // enqueue qualifying lane-maxes
    #pragma unroll
    for (int rt = 0; rt < 4; ++rt)
        #pragma unroll
        for (int reg = 0; reg < 4; ++reg) {
            int s = rt * 4 + reg;
            int rowloc = rt * 16 + q * 4 + reg;
            if (rm[s] >= rowth[rowloc]) {
                int pos = atomicAdd(&qn[wave], 1);
                if (pos < QW)
                    qbuf[wave][pos] = make_int2(__float_as_int(rm[s]),
                                                (rowloc << 11) | ri[s]);
            }
        }
    // final filtered drain
    {
        int hi = qn[wave]; if (hi > QW) hi = QW;
        drainq(qbuf[wave], 0, hi, lane, cn, en, b, row0, bestw[wave], rowth, true);
    }
    __syncthreads();
    if (tid < 64) {
        unsigned long long bb = bestw[0][tid];
        #pragma unroll
        for (int w = 1; w < 8; ++w) { unsigned long long t2 = bestw[w][tid]; if (t2 > bb) bb = t2; }
        finalidx[b * L_ + row0 + tid] = 2047 - (int)(bb & 0x7FFULL);
    }
}

// ---------------- K3: g[r] = relu(X[r]@W1+b1)@W2 + b2, fp32, BM=128 8x8 ----------------
__global__ __launch_bounds__(256) void k_feval(
        const float* __restrict__ X,
        const float* __restrict__ W1, const float* __restrict__ b1,
        const float* __restrict__ W2, const float* __restrict__ b2,
        float* __restrict__ g) {
    __shared__ __align__(16) float As[32][132];
    __shared__ __align__(16) float Bs[32][132];
    __shared__ float redv[128][16];

    int tid = threadIdx.x;
    int tx = tid & 15, ty = tid >> 4;
    int r  = tid >> 3, kg = tid & 7;
    int row0 = blockIdx.x * 128;
    const float* Ab = X + (size_t)row0 * D_;

    float acc[8][8];
    #pragma unroll
    for (int i = 0; i < 8; ++i)
        #pragma unroll
        for (int j = 0; j < 8; ++j) acc[i][j] = 0.0f;

    for (int kc = 0; kc < 4; ++kc) {
        __syncthreads();
        #pragma unroll
        for (int p = 0; p < 4; ++p) {
            int rr = r + 32 * p;
            float4 v = *(const float4*)(Ab + (size_t)rr * D_ + kc * 32 + kg * 4);
            As[kg][rr]      = v.x;
            As[8 + kg][rr]  = v.y;
            As[16 + kg][rr] = v.z;
            As[24 + kg][rr] = v.w;
        }
        {
            int kr = r, phys = (kr & 3) * 8 + (kr >> 2);
            const float* srcp = W1 + (size_t)(kc * 32 + kr) * D_ + kg * 16;
            #pragma unroll
            for (int qq = 0; qq < 4; ++qq)
                *(float4*)&Bs[phys][kg * 16 + qq * 4] = *(const float4*)(srcp + qq * 4);
        }
        __syncthreads();
        #pragma unroll
        for (int k = 0; k < 32; ++k) {
            float a[8], bb[8];
            *(float4*)&a[0]  = *(const float4*)&As[k][ty * 4];
            *(float4*)&a[4]  = *(const float4*)&As[k][64 + ty * 4];
            *(float4*)&bb[0] = *(const float4*)&Bs[k][tx * 4];
            *(float4*)&bb[4] = *(const float4*)&Bs[k][64 + tx * 4];
            #pragma unroll
            for (int i = 0; i < 8; ++i)
                #pragma unroll
                for (int j = 0; j < 8; ++j)
                    acc[i][j] = fmaf(a[i], bb[j], acc[i][j]);
        }
    }

    float w2j[8], b1j[8];
    #pragma unroll
    for (int jj = 0; jj < 8; ++jj) {
        int c = (jj < 4) ? (tx * 4 + jj) : (64 + tx * 4 + (jj - 4));
        w2j[jj] = W2[c];
        b1j[jj] = b1[c];
    }
    float bias2 = b2[0];
    __syncthreads();
    #pragma unroll
    for (int i = 0; i < 8; ++i) {
        float s = 0.0f;
        #pragma unroll
        for (int jj = 0; jj < 8; ++jj)
            s += fmaxf(acc[i][jj] + b1j[jj], 0.0f) * w2j[jj];
        int rowl = (i < 4) ? (ty * 4 + i) : (64 + ty * 4 + (i - 4));
        redv[rowl][tx] = s;
    }
    __syncthreads();
    if (tid < 128) {
        float s = 0.0f;
        #pragma unroll
        for (int tt = 0; tt < 16; ++tt) s += redv[tid][tt];
        g[row0 + tid] = s + bias2;
    }
}

// ---------------- K4: output ----------------
__global__ void k_out(const int* __restrict__ finalidx,
                      const float* __restrict__ g, float* __restrict__ out) {
    int rr = blockIdx.x * 256 + threadIdx.x;
    if (rr >= BL_) return;
    int b = rr >> 11;
    out[rr] = g[rr] + g[BL_ + (b << 11) + finalidx[rr]];
}

extern "C" void kernel_launch(void* const* d_in, const int* in_sizes, int n_in,
                              void* d_out, int out_size, void* d_ws, size_t ws_size,
                              hipStream_t stream) {
    const float* context = (const float*)d_in[0];
    const float* W1 = (const float*)d_in[1];
    const float* b1 = (const float*)d_in[2];
    const float* W2 = (const float*)d_in[3];
    const float* b2 = (const float*)d_in[4];
    float* out = (float*)d_out;

    char* ws = (char*)d_ws;
    float*  cn  = (float*)(ws);                  // 8 MB
    float*  en  = (float*)(ws + 8388608);        // 8 MB
    ushort* cnb = (ushort*)(ws + 16777216);      // 4 MB
    ushort* enb = (ushort*)(ws + 20971520);      // 4 MB
    float*  g   = (float*)(ws + 25165824);       // 128 KB
    int* finalidx = (int*)(ws + 25296896);       // 64 KB

    k_norm<<<8192, 256, 0, stream>>>(context, cn, en, cnb, enb);
    k_sim<<<256, 512, 0, stream>>>(cnb, enb, cn, en, finalidx);
    k_feval<<<256, 256, 0, stream>>>(cn, W1, b1, W2, b2, g);
    k_out<<<BL_ / 256, 256, 0, stream>>>(finalidx, g, out);
}

// Round 7
// 217.175 us; speedup vs baseline: 3.1430x; 3.1430x over previous
//
#include <hip/hip_runtime.h>
#include <hip/hip_bf16.h>

#define B_ 8
#define L_ 2048
#define D_ 128
#define BL_ (B_ * L_)
#define DELTA2 0.016f   // 2*delta; rigorous bf16 dot bound ~0.008, 2x margin
#define QW 1280         // per-wave queue capacity

typedef __attribute__((ext_vector_type(8))) short bf16x8;
typedef __attribute__((ext_vector_type(4))) float f32x4;

// ---------------- K1: normalize + bf16 cast ----------------
__global__ void k_norm(const float* __restrict__ ctx,
                       float* __restrict__ cn, float* __restrict__ en,
                       ushort* __restrict__ cnb, ushort* __restrict__ enb) {
    int wid  = blockIdx.x * 4 + (threadIdx.x >> 6);
    int lane = threadIdx.x & 63;
    int b   = wid >> 12;
    int rem = wid & 4095;
    int c   = rem >> 11;
    int l   = rem & 2047;

    const float* src = ctx + (size_t)wid * D_;
    float2 v = ((const float2*)src)[lane];
    float ss = v.x * v.x + v.y * v.y;
    #pragma unroll
    for (int off = 32; off; off >>= 1) ss += __shfl_down(ss, off, 64);
    ss = __shfl(ss, 0, 64);
    float n = fmaxf(sqrtf(ss), 1e-8f);
    float ox = v.x / n, oy = v.y / n;

    size_t ro = (size_t)(b * L_ + l) * D_;
    float* dst = (c == 0 ? cn : en) + ro;
    ((float2*)dst)[lane] = make_float2(ox, oy);

    __hip_bfloat16 hx = __float2bfloat16(ox), hy = __float2bfloat16(oy);
    ushort ux = *(ushort*)&hx, uy = *(ushort*)&hy;
    ushort* dstb = (c == 0 ? cnb : enb) + ro;
    ((ushort2*)dstb)[lane] = make_ushort2(ux, uy);
}

// wave-cooperative exact double dots for queued (row,col) candidates
__device__ __forceinline__ void drainq(const int* qw, int hi, int lane,
                                       const float* __restrict__ cn,
                                       const float* __restrict__ en,
                                       int b, int row0,
                                       unsigned long long* bw) {
    for (int e = 0; e < hi; ++e) {
        int rc = qw[e];
        int rowloc = rc >> 11, col = rc & 2047;
        const float* ar = cn + ((size_t)(b * L_) + row0 + rowloc) * D_;
        const float* br = en + ((size_t)(b * L_) + col) * D_;
        float2 x = ((const float2*)ar)[lane];
        float2 y = ((const float2*)br)[lane];
        double s = (double)x.x * y.x + (double)x.y * y.y;
        #pragma unroll
        for (int off = 32; off; off >>= 1) s += __shfl_down(s, off, 64);
        if (lane == 0) {
            unsigned long long ub = (unsigned long long)__double_as_longlong(s);
            ub = (ub & 0x8000000000000000ULL) ? ~ub : (ub | 0x8000000000000000ULL);
            ub = (ub & ~0x7FFULL) | (unsigned long long)(2047 - col);  // tie -> lowest col
            if (ub > bw[rowloc]) bw[rowloc] = ub;
        }
    }
}

// ---------------- K2: sim + argmax, two pipelined passes + exact repair ----------------
// grid 256: b = blk&7 (XCD), rb = blk>>3. Block = 64 rows x 2048 cols, 8 waves;
// wave w owns cols [w*256,(w+1)*256) = 4 tiles of 64x64; 16 flat (t,kc) stages,
// distance-2 prefetch with triple-buffered B fragments.
__global__ __launch_bounds__(512) void k_sim(const ushort* __restrict__ cnb,
                                             const ushort* __restrict__ enb,
                                             const float* __restrict__ cn,
                                             const float* __restrict__ en,
                                             int* __restrict__ finalidx) {
    __shared__ int qbuf[8][QW];                     // 40 KB
    __shared__ unsigned long long bestw[8][64];     // 4 KB
    __shared__ float wrowmax[8][64];                // 2 KB
    __shared__ float rowth[64];
    __shared__ int qn[8];

    int bid = blockIdx.x;
    int b = bid & 7, rb = bid >> 3;
    int row0 = rb * 64;
    int tid = threadIdx.x;
    int wave = tid >> 6, lane = tid & 63;
    int m = lane & 15, q = lane >> 4;

    if (lane == 0) qn[wave] = 0;
    bestw[wave][lane] = 0ULL;

    const ushort* Ab  = cnb + ((size_t)(b * L_) + row0) * D_;
    const ushort* Bb0 = enb + (size_t)(b * L_) * D_;
    int colw = wave * 256;

    bf16x8 Areg[16];
    #pragma unroll
    for (int rt = 0; rt < 4; ++rt)
        #pragma unroll
        for (int kc = 0; kc < 4; ++kc)
            Areg[rt * 4 + kc] = *(const bf16x8*)(Ab + (size_t)(rt * 16 + m) * D_ + kc * 32 + q * 8);

    float rm[16];
    #pragma unroll
    for (int s = 0; s < 16; ++s) rm[s] = -3.0e38f;

    f32x4 acc[4][4];
    bf16x8 Bbuf[3][4];

    // ======== PASS 1: per-row max ========
    #pragma unroll
    for (int ps = 0; ps < 2; ++ps) {
        const int t = ps >> 2, kc = ps & 3;
        #pragma unroll
        for (int ct = 0; ct < 4; ++ct)
            Bbuf[ps][ct] = *(const bf16x8*)(
                Bb0 + (size_t)(colw + t * 64 + ct * 16 + m) * D_ + kc * 32 + q * 8);
    }
    #pragma unroll
    for (int s = 0; s < 16; ++s) {
        const int t = s >> 2, kc = s & 3;
        if (s + 2 < 16) {
            const int nt = (s + 2) >> 2, nkc = (s + 2) & 3;
            #pragma unroll
            for (int ct = 0; ct < 4; ++ct)
                Bbuf[(s + 2) % 3][ct] = *(const bf16x8*)(
                    Bb0 + (size_t)(colw + nt * 64 + ct * 16 + m) * D_ + nkc * 32 + q * 8);
        }
        if (kc == 0) {
            #pragma unroll
            for (int rt = 0; rt < 4; ++rt)
                #pragma unroll
                for (int ct = 0; ct < 4; ++ct) acc[rt][ct] = (f32x4){0.f, 0.f, 0.f, 0.f};
        }
        #pragma unroll
        for (int rt = 0; rt < 4; ++rt)
            #pragma unroll
            for (int ct = 0; ct < 4; ++ct)
                acc[rt][ct] = __builtin_amdgcn_mfma_f32_16x16x32_bf16(
                    Areg[rt * 4 + kc], Bbuf[s % 3][ct], acc[rt][ct], 0, 0, 0);
        if (kc == 3) {
            #pragma unroll
            for (int rt = 0; rt < 4; ++rt)
                #pragma unroll
                for (int reg = 0; reg < 4; ++reg) {
                    float v = fmaxf(fmaxf(acc[rt][0][reg], acc[rt][1][reg]),
                                    fmaxf(acc[rt][2][reg], acc[rt][3][reg]));
                    rm[rt * 4 + reg] = fmaxf(rm[rt * 4 + reg], v);
                }
        }
    }

    // block row-max -> threshold
    #pragma unroll
    for (int rt = 0; rt < 4; ++rt)
        #pragma unroll
        for (int reg = 0; reg < 4; ++reg) {
            float v = rm[rt * 4 + reg];
            v = fmaxf(v, __shfl_xor(v, 1, 64));
            v = fmaxf(v, __shfl_xor(v, 2, 64));
            v = fmaxf(v, __shfl_xor(v, 4, 64));
            v = fmaxf(v, __shfl_xor(v, 8, 64));
            if (m == 0) wrowmax[wave][rt * 16 + q * 4 + reg] = v;
        }
    __syncthreads();
    if (tid < 64) {
        float rmx = wrowmax[0][tid];
        #pragma unroll
        for (int w = 1; w < 8; ++w) rmx = fmaxf(rmx, wrowmax[w][tid]);
        rowth[tid] = rmx - DELTA2;
    }
    __syncthreads();
    float rowth_r[16];
    #pragma unroll
    for (int rt = 0; rt < 4; ++rt)
        #pragma unroll
        for (int reg = 0; reg < 4; ++reg)
            rowth_r[rt * 4 + reg] = rowth[rt * 16 + q * 4 + reg];

    // ======== PASS 2: recompute (deterministic), enqueue >= rowmax - 2*delta ========
    #pragma unroll
    for (int ps = 0; ps < 2; ++ps) {
        const int t = ps >> 2, kc = ps & 3;
        #pragma unroll
        for (int ct = 0; ct < 4; ++ct)
            Bbuf[ps][ct] = *(const bf16x8*)(
                Bb0 + (size_t)(colw + t * 64 + ct * 16 + m) * D_ + kc * 32 + q * 8);
    }
    #pragma unroll
    for (int s = 0; s < 16; ++s) {
        const int t = s >> 2, kc = s & 3;
        if (s + 2 < 16) {
            const int nt = (s + 2) >> 2, nkc = (s + 2) & 3;
            #pragma unroll
            for (int ct = 0; ct < 4; ++ct)
                Bbuf[(s + 2) % 3][ct] = *(const bf16x8*)(
                    Bb0 + (size_t)(colw + nt * 64 + ct * 16 + m) * D_ + nkc * 32 + q * 8);
        }
        if (kc == 0) {
            #pragma unroll
            for (int rt = 0; rt < 4; ++rt)
                #pragma unroll
                for (int ct = 0; ct < 4; ++ct) acc[rt][ct] = (f32x4){0.f, 0.f, 0.f, 0.f};
        }
        #pragma unroll
        for (int rt = 0; rt < 4; ++rt)
            #pragma unroll
            for (int ct = 0; ct < 4; ++ct)
                acc[rt][ct] = __builtin_amdgcn_mfma_f32_16x16x32_bf16(
                    Areg[rt * 4 + kc], Bbuf[s % 3][ct], acc[rt][ct], 0, 0, 0);
        if (kc == 3) {
            int col0 = colw + t * 64;
            // safety drain (unreachable for random data; keeps correctness under overflow)
            if (qn[wave] > QW - 1024) {
                int hi = qn[wave]; if (hi > QW) hi = QW;
                drainq(qbuf[wave], hi, lane, cn, en, b, row0, bestw[wave]);
                if (lane == 0) qn[wave] = 0;
            }
            #pragma unroll
            for (int rt = 0; rt < 4; ++rt)
                #pragma unroll
                for (int reg = 0; reg < 4; ++reg) {
                    float th = rowth_r[rt * 4 + reg];
                    float mx = fmaxf(fmaxf(acc[rt][0][reg], acc[rt][1][reg]),
                                     fmaxf(acc[rt][2][reg], acc[rt][3][reg]));
                    if (mx >= th) {
                        int rowloc = rt * 16 + q * 4 + reg;
                        #pragma unroll
                        for (int ct = 0; ct < 4; ++ct)
                            if (acc[rt][ct][reg] >= th) {
                                int pos = atomicAdd(&qn[wave], 1);
                                if (pos < QW)
                                    qbuf[wave][pos] = (rowloc << 11) | (col0 + ct * 16 + m);
                            }
                    }
                }
        }
    }

    // final drain + merge
    {
        int hi = qn[wave]; if (hi > QW) hi = QW;
        drainq(qbuf[wave], hi, lane, cn, en, b, row0, bestw[wave]);
    }
    __syncthreads();
    if (tid < 64) {
        unsigned long long bb = bestw[0][tid];
        #pragma unroll
        for (int w = 1; w < 8; ++w) { unsigned long long t2 = bestw[w][tid]; if (t2 > bb) bb = t2; }
        finalidx[b * L_ + row0 + tid] = 2047 - (int)(bb & 0x7FFULL);
    }
}

// ---------------- K3: g[r] = relu(X[r]@W1+b1)@W2 + b2, fp32, BM=128 8x8 ----------------
__global__ __launch_bounds__(256) void k_feval(
        const float* __restrict__ X,
        const float* __restrict__ W1, const float* __restrict__ b1,
        const float* __restrict__ W2, const float* __restrict__ b2,
        float* __restrict__ g) {
    __shared__ __align__(16) float As[32][132];
    __shared__ __align__(16) float Bs[32][132];
    __shared__ float redv[128][16];

    int tid = threadIdx.x;
    int tx = tid & 15, ty = tid >> 4;
    int r  = tid >> 3, kg = tid & 7;
    int row0 = blockIdx.x * 128;
    const float* Ab = X + (size_t)row0 * D_;

    float acc[8][8];
    #pragma unroll
    for (int i = 0; i < 8; ++i)
        #pragma unroll
        for (int j = 0; j < 8; ++j) acc[i][j] = 0.0f;

    for (int kc = 0; kc < 4; ++kc) {
        __syncthreads();
        #pragma unroll
        for (int p = 0; p < 4; ++p) {
            int rr = r + 32 * p;
            float4 v = *(const float4*)(Ab + (size_t)rr * D_ + kc * 32 + kg * 4);
            As[kg][rr]      = v.x;
            As[8 + kg][rr]  = v.y;
            As[16 + kg][rr] = v.z;
            As[24 + kg][rr] = v.w;
        }
        {
            int kr = r, phys = (kr & 3) * 8 + (kr >> 2);
            const float* srcp = W1 + (size_t)(kc * 32 + kr) * D_ + kg * 16;
            #pragma unroll
            for (int qq = 0; qq < 4; ++qq)
                *(float4*)&Bs[phys][kg * 16 + qq * 4] = *(const float4*)(srcp + qq * 4);
        }
        __syncthreads();
        #pragma unroll
        for (int k = 0; k < 32; ++k) {
            float a[8], bb[8];
            *(float4*)&a[0]  = *(const float4*)&As[k][ty * 4];
            *(float4*)&a[4]  = *(const float4*)&As[k][64 + ty * 4];
            *(float4*)&bb[0] = *(const float4*)&Bs[k][tx * 4];
            *(float4*)&bb[4] = *(const float4*)&Bs[k][64 + tx * 4];
            #pragma unroll
            for (int i = 0; i < 8; ++i)
                #pragma unroll
                for (int j = 0; j < 8; ++j)
                    acc[i][j] = fmaf(a[i], bb[j], acc[i][j]);
        }
    }

    float w2j[8], b1j[8];
    #pragma unroll
    for (int jj = 0; jj < 8; ++jj) {
        int c = (jj < 4) ? (tx * 4 + jj) : (64 + tx * 4 + (jj - 4));
        w2j[jj] = W2[c];
        b1j[jj] = b1[c];
    }
    float bias2 = b2[0];
    __syncthreads();
    #pragma unroll
    for (int i = 0; i < 8; ++i) {
        float s = 0.0f;
        #pragma unroll
        for (int jj = 0; jj < 8; ++jj)
            s += fmaxf(acc[i][jj] + b1j[jj], 0.0f) * w2j[jj];
        int rowl = (i < 4) ? (ty * 4 + i) : (64 + ty * 4 + (i - 4));
        redv[rowl][tx] = s;
    }
    __syncthreads();
    if (tid < 128) {
        float s = 0.0f;
        #pragma unroll
        for (int tt = 0; tt < 16; ++tt) s += redv[tid][tt];
        g[row0 + tid] = s + bias2;
    }
}

// ---------------- K4: output ----------------
__global__ void k_out(const int* __restrict__ finalidx,
                      const float* __restrict__ g, float* __restrict__ out) {
    int rr = blockIdx.x * 256 + threadIdx.x;
    if (rr >= BL_) return;
    int b = rr >> 11;
    out[rr] = g[rr] + g[BL_ + (b << 11) + finalidx[rr]];
}

extern "C" void kernel_launch(void* const* d_in, const int* in_sizes, int n_in,
                              void* d_out, int out_size, void* d_ws, size_t ws_size,
                              hipStream_t stream) {
    const float* context = (const float*)d_in[0];
    const float* W1 = (const float*)d_in[1];
    const float* b1 = (const float*)d_in[2];
    const float* W2 = (const float*)d_in[3];
    const float* b2 = (const float*)d_in[4];
    float* out = (float*)d_out;

    char* ws = (char*)d_ws;
    float*  cn  = (float*)(ws);                  // 8 MB
    float*  en  = (float*)(ws + 8388608);        // 8 MB
    ushort* cnb = (ushort*)(ws + 16777216);      // 4 MB
    ushort* enb = (ushort*)(ws + 20971520);      // 4 MB
    float*  g   = (float*)(ws + 25165824);       // 128 KB
    int* finalidx = (int*)(ws + 25296896);       // 64 KB

    k_norm<<<8192, 256, 0, stream>>>(context, cn, en, cnb, enb);
    k_sim<<<256, 512, 0, stream>>>(cnb, enb, cn, en, finalidx);
    k_feval<<<256, 256, 0, stream>>>(cn, W1, b1, W2, b2, g);
    k_out<<<BL_ / 256, 256, 0, stream>>>(finalidx, g, out);
}

// Round 8
// 216.765 us; speedup vs baseline: 3.1490x; 1.0019x over previous
//
#include <hip/hip_runtime.h>
#include <hip/hip_bf16.h>

#define B_ 8
#define L_ 2048
#define D_ 128
#define BL_ (B_ * L_)
#define DELTA2 0.016f   // 2*delta; rigorous bf16 dot bound ~0.008, 2x margin
#define QW 1280         // per-wave queue capacity

typedef __attribute__((ext_vector_type(8))) short bf16x8;
typedef __attribute__((ext_vector_type(4))) float f32x4;

// ---------------- K1: normalize + bf16 cast ----------------
__global__ void k_norm(const float* __restrict__ ctx,
                       float* __restrict__ cn, float* __restrict__ en,
                       ushort* __restrict__ cnb, ushort* __restrict__ enb) {
    int wid  = blockIdx.x * 4 + (threadIdx.x >> 6);
    int lane = threadIdx.x & 63;
    int b   = wid >> 12;
    int rem = wid & 4095;
    int c   = rem >> 11;
    int l   = rem & 2047;

    const float* src = ctx + (size_t)wid * D_;
    float2 v = ((const float2*)src)[lane];
    float ss = v.x * v.x + v.y * v.y;
    #pragma unroll
    for (int off = 32; off; off >>= 1) ss += __shfl_down(ss, off, 64);
    ss = __shfl(ss, 0, 64);
    float n = fmaxf(sqrtf(ss), 1e-8f);
    float ox = v.x / n, oy = v.y / n;

    size_t ro = (size_t)(b * L_ + l) * D_;
    float* dst = (c == 0 ? cn : en) + ro;
    ((float2*)dst)[lane] = make_float2(ox, oy);

    __hip_bfloat16 hx = __float2bfloat16(ox), hy = __float2bfloat16(oy);
    ushort ux = *(ushort*)&hx, uy = *(ushort*)&hy;
    ushort* dstb = (c == 0 ? cnb : enb) + ro;
    ((ushort2*)dstb)[lane] = make_ushort2(ux, uy);
}

// wave-cooperative exact double dots for queued (row,col) candidates
__device__ __forceinline__ void drainq(const int* qw, int hi, int lane,
                                       const float* __restrict__ cn,
                                       const float* __restrict__ en,
                                       int b, int row0,
                                       unsigned long long* bw) {
    for (int e = 0; e < hi; ++e) {
        int rc = qw[e];
        int rowloc = rc >> 11, col = rc & 2047;
        const float* ar = cn + ((size_t)(b * L_) + row0 + rowloc) * D_;
        const float* br = en + ((size_t)(b * L_) + col) * D_;
        float2 x = ((const float2*)ar)[lane];
        float2 y = ((const float2*)br)[lane];
        double s = (double)x.x * y.x + (double)x.y * y.y;
        #pragma unroll
        for (int off = 32; off; off >>= 1) s += __shfl_down(s, off, 64);
        if (lane == 0) {
            unsigned long long ub = (unsigned long long)__double_as_longlong(s);
            ub = (ub & 0x8000000000000000ULL) ? ~ub : (ub | 0x8000000000000000ULL);
            ub = (ub & ~0x7FFULL) | (unsigned long long)(2047 - col);  // tie -> lowest col
            if (ub > bw[rowloc]) bw[rowloc] = ub;
        }
    }
}

// ---------------- K2: sim + argmax, two pipelined passes + exact repair ----------------
// grid 256: b = blk&7 (XCD), rb = blk>>3. Block = 64 rows x 2048 cols, 8 waves;
// wave w owns cols [w*256,(w+1)*256) = 4 tiles of 64x64; 16 flat (t,kc) stages,
// distance-2 prefetch with triple-buffered B fragments.
// __launch_bounds__(512, 2): 2 waves/EU = 1 block/CU -> 256 VGPR/wave; the ~220-reg
// live set (Areg 64 + acc 64 + Bbuf 48 + bookkeeping) MUST NOT spill (r7: cap=128
// spilled acc -> 283 MB scratch writes, kernel 128 us).
__global__ __launch_bounds__(512, 2) void k_sim(const ushort* __restrict__ cnb,
                                                const ushort* __restrict__ enb,
                                                const float* __restrict__ cn,
                                                const float* __restrict__ en,
                                                int* __restrict__ finalidx) {
    __shared__ int qbuf[8][QW];                     // 40 KB
    __shared__ unsigned long long bestw[8][64];     // 4 KB
    __shared__ float wrowmax[8][64];                // 2 KB
    __shared__ float rowth[64];
    __shared__ int qn[8];

    int bid = blockIdx.x;
    int b = bid & 7, rb = bid >> 3;
    int row0 = rb * 64;
    int tid = threadIdx.x;
    int wave = tid >> 6, lane = tid & 63;
    int m = lane & 15, q = lane >> 4;

    if (lane == 0) qn[wave] = 0;
    bestw[wave][lane] = 0ULL;

    const ushort* Ab  = cnb + ((size_t)(b * L_) + row0) * D_;
    const ushort* Bb0 = enb + (size_t)(b * L_) * D_;
    int colw = wave * 256;

    bf16x8 Areg[16];
    #pragma unroll
    for (int rt = 0; rt < 4; ++rt)
        #pragma unroll
        for (int kc = 0; kc < 4; ++kc)
            Areg[rt * 4 + kc] = *(const bf16x8*)(Ab + (size_t)(rt * 16 + m) * D_ + kc * 32 + q * 8);

    float rm[16];
    #pragma unroll
    for (int s = 0; s < 16; ++s) rm[s] = -3.0e38f;

    f32x4 acc[4][4];
    bf16x8 Bbuf[3][4];

    // ======== PASS 1: per-row max ========
    #pragma unroll
    for (int ps = 0; ps < 2; ++ps) {
        const int t = ps >> 2, kc = ps & 3;
        #pragma unroll
        for (int ct = 0; ct < 4; ++ct)
            Bbuf[ps][ct] = *(const bf16x8*)(
                Bb0 + (size_t)(colw + t * 64 + ct * 16 + m) * D_ + kc * 32 + q * 8);
    }
    #pragma unroll
    for (int s = 0; s < 16; ++s) {
        const int t = s >> 2, kc = s & 3;
        if (s + 2 < 16) {
            const int nt = (s + 2) >> 2, nkc = (s + 2) & 3;
            #pragma unroll
            for (int ct = 0; ct < 4; ++ct)
                Bbuf[(s + 2) % 3][ct] = *(const bf16x8*)(
                    Bb0 + (size_t)(colw + nt * 64 + ct * 16 + m) * D_ + nkc * 32 + q * 8);
        }
        if (kc == 0) {
            #pragma unroll
            for (int rt = 0; rt < 4; ++rt)
                #pragma unroll
                for (int ct = 0; ct < 4; ++ct) acc[rt][ct] = (f32x4){0.f, 0.f, 0.f, 0.f};
        }
        #pragma unroll
        for (int rt = 0; rt < 4; ++rt)
            #pragma unroll
            for (int ct = 0; ct < 4; ++ct)
                acc[rt][ct] = __builtin_amdgcn_mfma_f32_16x16x32_bf16(
                    Areg[rt * 4 + kc], Bbuf[s % 3][ct], acc[rt][ct], 0, 0, 0);
        if (kc == 3) {
            #pragma unroll
            for (int rt = 0; rt < 4; ++rt)
                #pragma unroll
                for (int reg = 0; reg < 4; ++reg) {
                    float v = fmaxf(fmaxf(acc[rt][0][reg], acc[rt][1][reg]),
                                    fmaxf(acc[rt][2][reg], acc[rt][3][reg]));
                    rm[rt * 4 + reg] = fmaxf(rm[rt * 4 + reg], v);
                }
        }
    }

    // block row-max -> threshold
    #pragma unroll
    for (int rt = 0; rt < 4; ++rt)
        #pragma unroll
        for (int reg = 0; reg < 4; ++reg) {
            float v = rm[rt * 4 + reg];
            v = fmaxf(v, __shfl_xor(v, 1, 64));
            v = fmaxf(v, __shfl_xor(v, 2, 64));
            v = fmaxf(v, __shfl_xor(v, 4, 64));
            v = fmaxf(v, __shfl_xor(v, 8, 64));
            if (m == 0) wrowmax[wave][rt * 16 + q * 4 + reg] = v;
        }
    __syncthreads();
    if (tid < 64) {
        float rmx = wrowmax[0][tid];
        #pragma unroll
        for (int w = 1; w < 8; ++w) rmx = fmaxf(rmx, wrowmax[w][tid]);
        rowth[tid] = rmx - DELTA2;
    }
    __syncthreads();
    float rowth_r[16];
    #pragma unroll
    for (int rt = 0; rt < 4; ++rt)
        #pragma unroll
        for (int reg = 0; reg < 4; ++reg)
            rowth_r[rt * 4 + reg] = rowth[rt * 16 + q * 4 + reg];

    // ======== PASS 2: recompute (deterministic), enqueue >= rowmax - 2*delta ========
    #pragma unroll
    for (int ps = 0; ps < 2; ++ps) {
        const int t = ps >> 2, kc = ps & 3;
        #pragma unroll
        for (int ct = 0; ct < 4; ++ct)
            Bbuf[ps][ct] = *(const bf16x8*)(
                Bb0 + (size_t)(colw + t * 64 + ct * 16 + m) * D_ + kc * 32 + q * 8);
    }
    #pragma unroll
    for (int s = 0; s < 16; ++s) {
        const int t = s >> 2, kc = s & 3;
        if (s + 2 < 16) {
            const int nt = (s + 2) >> 2, nkc = (s + 2) & 3;
            #pragma unroll
            for (int ct = 0; ct < 4; ++ct)
                Bbuf[(s + 2) % 3][ct] = *(const bf16x8*)(
                    Bb0 + (size_t)(colw + nt * 64 + ct * 16 + m) * D_ + nkc * 32 + q * 8);
        }
        if (kc == 0) {
            #pragma unroll
            for (int rt = 0; rt < 4; ++rt)
                #pragma unroll
                for (int ct = 0; ct < 4; ++ct) acc[rt][ct] = (f32x4){0.f, 0.f, 0.f, 0.f};
        }
        #pragma unroll
        for (int rt = 0; rt < 4; ++rt)
            #pragma unroll
            for (int ct = 0; ct < 4; ++ct)
                acc[rt][ct] = __builtin_amdgcn_mfma_f32_16x16x32_bf16(
                    Areg[rt * 4 + kc], Bbuf[s % 3][ct], acc[rt][ct], 0, 0, 0);
        if (kc == 3) {
            int col0 = colw + t * 64;
            // safety drain (unreachable for random data; keeps correctness under overflow)
            if (qn[wave] > QW - 1024) {
                int hi = qn[wave]; if (hi > QW) hi = QW;
                drainq(qbuf[wave], hi, lane, cn, en, b, row0, bestw[wave]);
                if (lane == 0) qn[wave] = 0;
            }
            #pragma unroll
            for (int rt = 0; rt < 4; ++rt)
                #pragma unroll
                for (int reg = 0; reg < 4; ++reg) {
                    float th = rowth_r[rt * 4 + reg];
                    float mx = fmaxf(fmaxf(acc[rt][0][reg], acc[rt][1][reg]),
                                     fmaxf(acc[rt][2][reg], acc[rt][3][reg]));
                    if (mx >= th) {
                        int rowloc = rt * 16 + q * 4 + reg;
                        #pragma unroll
                        for (int ct = 0; ct < 4; ++ct)
                            if (acc[rt][ct][reg] >= th) {
                                int pos = atomicAdd(&qn[wave], 1);
                                if (pos < QW)
                                    qbuf[wave][pos] = (rowloc << 11) | (col0 + ct * 16 + m);
                            }
                    }
                }
        }
    }

    // final drain + merge
    {
        int hi = qn[wave]; if (hi > QW) hi = QW;
        drainq(qbuf[wave], hi, lane, cn, en, b, row0, bestw[wave]);
    }
    __syncthreads();
    if (tid < 64) {
        unsigned long long bb = bestw[0][tid];
        #pragma unroll
        for (int w = 1; w < 8; ++w) { unsigned long long t2 = bestw[w][tid]; if (t2 > bb) bb = t2; }
        finalidx[b * L_ + row0 + tid] = 2047 - (int)(bb & 0x7FFULL);
    }
}

// ---------------- K3: g[r] = relu(X[r]@W1+b1)@W2 + b2, fp32, BM=128 8x8 ----------------
__global__ __launch_bounds__(256) void k_feval(
        const float* __restrict__ X,
        const float* __restrict__ W1, const float* __restrict__ b1,
        const float* __restrict__ W2, const float* __restrict__ b2,
        float* __restrict__ g) {
    __shared__ __align__(16) float As[32][132];
    __shared__ __align__(16) float Bs[32][132];
    __shared__ float redv[128][16];

    int tid = threadIdx.x;
    int tx = tid & 15, ty = tid >> 4;
    int r  = tid >> 3, kg = tid & 7;
    int row0 = blockIdx.x * 128;
    const float* Ab = X + (size_t)row0 * D_;

    float acc[8][8];
    #pragma unroll
    for (int i = 0; i < 8; ++i)
        #pragma unroll
        for (int j = 0; j < 8; ++j) acc[i][j] = 0.0f;

    for (int kc = 0; kc < 4; ++kc) {
        __syncthreads();
        #pragma unroll
        for (int p = 0; p < 4; ++p) {
            int rr = r + 32 * p;
            float4 v = *(const float4*)(Ab + (size_t)rr * D_ + kc * 32 + kg * 4);
            As[kg][rr]      = v.x;
            As[8 + kg][rr]  = v.y;
            As[16 + kg][rr] = v.z;
            As[24 + kg][rr] = v.w;
        }
        {
            int kr = r, phys = (kr & 3) * 8 + (kr >> 2);
            const float* srcp = W1 + (size_t)(kc * 32 + kr) * D_ + kg * 16;
            #pragma unroll
            for (int qq = 0; qq < 4; ++qq)
                *(float4*)&Bs[phys][kg * 16 + qq * 4] = *(const float4*)(srcp + qq * 4);
        }
        __syncthreads();
        #pragma unroll
        for (int k = 0; k < 32; ++k) {
            float a[8], bb[8];
            *(float4*)&a[0]  = *(const float4*)&As[k][ty * 4];
            *(float4*)&a[4]  = *(const float4*)&As[k][64 + ty * 4];
            *(float4*)&bb[0] = *(const float4*)&Bs[k][tx * 4];
            *(float4*)&bb[4] = *(const float4*)&Bs[k][64 + tx * 4];
            #pragma unroll
            for (int i = 0; i < 8; ++i)
                #pragma unroll
                for (int j = 0; j < 8; ++j)
                    acc[i][j] = fmaf(a[i], bb[j], acc[i][j]);
        }
    }

    float w2j[8], b1j[8];
    #pragma unroll
    for (int jj = 0; jj < 8; ++jj) {
        int c = (jj < 4) ? (tx * 4 + jj) : (64 + tx * 4 + (jj - 4));
        w2j[jj] = W2[c];
        b1j[jj] = b1[c];
    }
    float bias2 = b2[0];
    __syncthreads();
    #pragma unroll
    for (int i = 0; i < 8; ++i) {
        float s = 0.0f;
        #pragma unroll
        for (int jj = 0; jj < 8; ++jj)
            s += fmaxf(acc[i][jj] + b1j[jj], 0.0f) * w2j[jj];
        int rowl = (i < 4) ? (ty * 4 + i) : (64 + ty * 4 + (i - 4));
        redv[rowl][tx] = s;
    }
    __syncthreads();
    if (tid < 128) {
        float s = 0.0f;
        #pragma unroll
        for (int tt = 0; tt < 16; ++tt) s += redv[tid][tt];
        g[row0 + tid] = s + bias2;
    }
}

// ---------------- K4: output ----------------
__global__ void k_out(const int* __restrict__ finalidx,
                      const float* __restrict__ g, float* __restrict__ out) {
    int rr = blockIdx.x * 256 + threadIdx.x;
    if (rr >= BL_) return;
    int b = rr >> 11;
    out[rr] = g[rr] + g[BL_ + (b << 11) + finalidx[rr]];
}

extern "C" void kernel_launch(void* const* d_in, const int* in_sizes, int n_in,
                              void* d_out, int out_size, void* d_ws, size_t ws_size,
                              hipStream_t stream) {
    const float* context = (const float*)d_in[0];
    const float* W1 = (const float*)d_in[1];
    const float* b1 = (const float*)d_in[2];
    const float* W2 = (const float*)d_in[3];
    const float* b2 = (const float*)d_in[4];
    float* out = (float*)d_out;

    char* ws = (char*)d_ws;
    float*  cn  = (float*)(ws);                  // 8 MB
    float*  en  = (float*)(ws + 8388608);        // 8 MB
    ushort* cnb = (ushort*)(ws + 16777216);      // 4 MB
    ushort* enb = (ushort*)(ws + 20971520);      // 4 MB
    float*  g   = (float*)(ws + 25165824);       // 128 KB
    int* finalidx = (int*)(ws + 25296896);       // 64 KB

    k_norm<<<8192, 256, 0, stream>>>(context, cn, en, cnb, enb);
    k_sim<<<256, 512, 0, stream>>>(cnb, enb, cn, en, finalidx);
    k_feval<<<256, 256, 0, stream>>>(cn, W1, b1, W2, b2, g);
    k_out<<<BL_ / 256, 256, 0, stream>>>(finalidx, g, out);
}

// Round 9
// 216.039 us; speedup vs baseline: 3.1596x; 1.0034x over previous
//
#include <hip/hip_runtime.h>
#include <hip/hip_bf16.h>

#define B_ 8
#define L_ 2048
#define D_ 128
#define BL_ (B_ * L_)
#define DELTA2 0.016f   // 2*delta; rigorous bf16 dot bound ~0.008, 2x margin
#define QW 1280         // per-wave queue capacity

typedef __attribute__((ext_vector_type(8))) short bf16x8;
typedef __attribute__((ext_vector_type(4))) float f32x4;

// ---------------- K1: normalize + bf16 cast ----------------
__global__ void k_norm(const float* __restrict__ ctx,
                       float* __restrict__ cn, float* __restrict__ en,
                       ushort* __restrict__ cnb, ushort* __restrict__ enb) {
    int wid  = blockIdx.x * 4 + (threadIdx.x >> 6);
    int lane = threadIdx.x & 63;
    int b   = wid >> 12;
    int rem = wid & 4095;
    int c   = rem >> 11;
    int l   = rem & 2047;

    const float* src = ctx + (size_t)wid * D_;
    float2 v = ((const float2*)src)[lane];
    float ss = v.x * v.x + v.y * v.y;
    #pragma unroll
    for (int off = 32; off; off >>= 1) ss += __shfl_down(ss, off, 64);
    ss = __shfl(ss, 0, 64);
    float n = fmaxf(sqrtf(ss), 1e-8f);
    float ox = v.x / n, oy = v.y / n;

    size_t ro = (size_t)(b * L_ + l) * D_;
    float* dst = (c == 0 ? cn : en) + ro;
    ((float2*)dst)[lane] = make_float2(ox, oy);

    __hip_bfloat16 hx = __float2bfloat16(ox), hy = __float2bfloat16(oy);
    ushort ux = *(ushort*)&hx, uy = *(ushort*)&hy;
    ushort* dstb = (c == 0 ? cnb : enb) + ro;
    ((ushort2*)dstb)[lane] = make_ushort2(ux, uy);
}

// wave-cooperative exact double dots for queued (row,col) candidates
__device__ __forceinline__ void drainq(const int* qw, int hi, int lane,
                                       const float* __restrict__ cn,
                                       const float* __restrict__ en,
                                       int b, int row0,
                                       unsigned long long* bw) {
    for (int e = 0; e < hi; ++e) {
        int rc = qw[e];
        int rowloc = rc >> 11, col = rc & 2047;
        const float* ar = cn + ((size_t)(b * L_) + row0 + rowloc) * D_;
        const float* br = en + ((size_t)(b * L_) + col) * D_;
        float2 x = ((const float2*)ar)[lane];
        float2 y = ((const float2*)br)[lane];
        double s = (double)x.x * y.x + (double)x.y * y.y;
        #pragma unroll
        for (int off = 32; off; off >>= 1) s += __shfl_down(s, off, 64);
        if (lane == 0) {
            unsigned long long ub = (unsigned long long)__double_as_longlong(s);
            ub = (ub & 0x8000000000000000ULL) ? ~ub : (ub | 0x8000000000000000ULL);
            ub = (ub & ~0x7FFULL) | (unsigned long long)(2047 - col);  // tie -> lowest col
            if (ub > bw[rowloc]) bw[rowloc] = ub;
        }
    }
}

// ---------------- K2: sim + argmax, two pipelined passes + exact repair ----------------
// grid 256: b = blk&7 (XCD), rb = blk>>3. Block = 64 rows x 2048 cols, 8 waves;
// wave w owns cols [w*256,(w+1)*256) = 4 tiles of 64x64; 16 flat (t,kc) stages,
// distance-2 prefetch with triple-buffered B fragments.
// __launch_bounds__(512, 1): the second arg acts as min BLOCKS/CU (CUDA semantics;
// r8 measured (512,2) -> VGPR cap 128 = 2 blocks/CU). 1 block/CU = 2 waves/SIMD
// -> VGPR cap 512. The ~220-reg live set (Areg 64 + acc 64 + Bbuf 48 + bookkeeping)
// MUST NOT spill (r7/r8: cap=128 -> 283 MB scratch writes, kernel 128 us).
__global__ __launch_bounds__(512, 1) void k_sim(const ushort* __restrict__ cnb,
                                                const ushort* __restrict__ enb,
                                                const float* __restrict__ cn,
                                                const float* __restrict__ en,
                                                int* __restrict__ finalidx) {
    __shared__ int qbuf[8][QW];                     // 40 KB
    __shared__ unsigned long long bestw[8][64];     // 4 KB
    __shared__ float wrowmax[8][64];                // 2 KB
    __shared__ float rowth[64];
    __shared__ int qn[8];

    int bid = blockIdx.x;
    int b = bid & 7, rb = bid >> 3;
    int row0 = rb * 64;
    int tid = threadIdx.x;
    int wave = tid >> 6, lane = tid & 63;
    int m = lane & 15, q = lane >> 4;

    if (lane == 0) qn[wave] = 0;
    bestw[wave][lane] = 0ULL;

    const ushort* Ab  = cnb + ((size_t)(b * L_) + row0) * D_;
    const ushort* Bb0 = enb + (size_t)(b * L_) * D_;
    int colw = wave * 256;

    bf16x8 Areg[16];
    #pragma unroll
    for (int rt = 0; rt < 4; ++rt)
        #pragma unroll
        for (int kc = 0; kc < 4; ++kc)
            Areg[rt * 4 + kc] = *(const bf16x8*)(Ab + (size_t)(rt * 16 + m) * D_ + kc * 32 + q * 8);

    float rm[16];
    #pragma unroll
    for (int s = 0; s < 16; ++s) rm[s] = -3.0e38f;

    f32x4 acc[4][4];
    bf16x8 Bbuf[3][4];

    // ======== PASS 1: per-row max ========
    #pragma unroll
    for (int ps = 0; ps < 2; ++ps) {
        const int t = ps >> 2, kc = ps & 3;
        #pragma unroll
        for (int ct = 0; ct < 4; ++ct)
            Bbuf[ps][ct] = *(const bf16x8*)(
                Bb0 + (size_t)(colw + t * 64 + ct * 16 + m) * D_ + kc * 32 + q * 8);
    }
    #pragma unroll
    for (int s = 0; s < 16; ++s) {
        const int t = s >> 2, kc = s & 3;
        if (s + 2 < 16) {
            const int nt = (s + 2) >> 2, nkc = (s + 2) & 3;
            #pragma unroll
            for (int ct = 0; ct < 4; ++ct)
                Bbuf[(s + 2) % 3][ct] = *(const bf16x8*)(
                    Bb0 + (size_t)(colw + nt * 64 + ct * 16 + m) * D_ + nkc * 32 + q * 8);
        }
        if (kc == 0) {
            #pragma unroll
            for (int rt = 0; rt < 4; ++rt)
                #pragma unroll
                for (int ct = 0; ct < 4; ++ct) acc[rt][ct] = (f32x4){0.f, 0.f, 0.f, 0.f};
        }
        #pragma unroll
        for (int rt = 0; rt < 4; ++rt)
            #pragma unroll
            for (int ct = 0; ct < 4; ++ct)
                acc[rt][ct] = __builtin_amdgcn_mfma_f32_16x16x32_bf16(
                    Areg[rt * 4 + kc], Bbuf[s % 3][ct], acc[rt][ct], 0, 0, 0);
        if (kc == 3) {
            #pragma unroll
            for (int rt = 0; rt < 4; ++rt)
                #pragma unroll
                for (int reg = 0; reg < 4; ++reg) {
                    float v = fmaxf(fmaxf(acc[rt][0][reg], acc[rt][1][reg]),
                                    fmaxf(acc[rt][2][reg], acc[rt][3][reg]));
                    rm[rt * 4 + reg] = fmaxf(rm[rt * 4 + reg], v);
                }
        }
    }

    // block row-max -> threshold
    #pragma unroll
    for (int rt = 0; rt < 4; ++rt)
        #pragma unroll
        for (int reg = 0; reg < 4; ++reg) {
            float v = rm[rt * 4 + reg];
            v = fmaxf(v, __shfl_xor(v, 1, 64));
            v = fmaxf(v, __shfl_xor(v, 2, 64));
            v = fmaxf(v, __shfl_xor(v, 4, 64));
            v = fmaxf(v, __shfl_xor(v, 8, 64));
            if (m == 0) wrowmax[wave][rt * 16 + q * 4 + reg] = v;
        }
    __syncthreads();
    if (tid < 64) {
        float rmx = wrowmax[0][tid];
        #pragma unroll
        for (int w = 1; w < 8; ++w) rmx = fmaxf(rmx, wrowmax[w][tid]);
        rowth[tid] = rmx - DELTA2;
    }
    __syncthreads();
    float rowth_r[16];
    #pragma unroll
    for (int rt = 0; rt < 4; ++rt)
        #pragma unroll
        for (int reg = 0; reg < 4; ++reg)
            rowth_r[rt * 4 + reg] = rowth[rt * 16 + q * 4 + reg];

    // ======== PASS 2: recompute (deterministic), enqueue >= rowmax - 2*delta ========
    #pragma unroll
    for (int ps = 0; ps < 2; ++ps) {
        const int t = ps >> 2, kc = ps & 3;
        #pragma unroll
        for (int ct = 0; ct < 4; ++ct)
            Bbuf[ps][ct] = *(const bf16x8*)(
                Bb0 + (size_t)(colw + t * 64 + ct * 16 + m) * D_ + kc * 32 + q * 8);
    }
    #pragma unroll
    for (int s = 0; s < 16; ++s) {
        const int t = s >> 2, kc = s & 3;
        if (s + 2 < 16) {
            const int nt = (s + 2) >> 2, nkc = (s + 2) & 3;
            #pragma unroll
            for (int ct = 0; ct < 4; ++ct)
                Bbuf[(s + 2) % 3][ct] = *(const bf16x8*)(
                    Bb0 + (size_t)(colw + nt * 64 + ct * 16 + m) * D_ + nkc * 32 + q * 8);
        }
        if (kc == 0) {
            #pragma unroll
            for (int rt = 0; rt < 4; ++rt)
                #pragma unroll
                for (int ct = 0; ct < 4; ++ct) acc[rt][ct] = (f32x4){0.f, 0.f, 0.f, 0.f};
        }
        #pragma unroll
        for (int rt = 0; rt < 4; ++rt)
            #pragma unroll
            for (int ct = 0; ct < 4; ++ct)
                acc[rt][ct] = __builtin_amdgcn_mfma_f32_16x16x32_bf16(
                    Areg[rt * 4 + kc], Bbuf[s % 3][ct], acc[rt][ct], 0, 0, 0);
        if (kc == 3) {
            int col0 = colw + t * 64;
            // safety drain (unreachable for random data; keeps correctness under overflow)
            if (qn[wave] > QW - 1024) {
                int hi = qn[wave]; if (hi > QW) hi = QW;
                drainq(qbuf[wave], hi, lane, cn, en, b, row0, bestw[wave]);
                if (lane == 0) qn[wave] = 0;
            }
            #pragma unroll
            for (int rt = 0; rt < 4; ++rt)
                #pragma unroll
                for (int reg = 0; reg < 4; ++reg) {
                    float th = rowth_r[rt * 4 + reg];
                    float mx = fmaxf(fmaxf(acc[rt][0][reg], acc[rt][1][reg]),
                                     fmaxf(acc[rt][2][reg], acc[rt][3][reg]));
                    if (mx >= th) {
                        int rowloc = rt * 16 + q * 4 + reg;
                        #pragma unroll
                        for (int ct = 0; ct < 4; ++ct)
                            if (acc[rt][ct][reg] >= th) {
                                int pos = atomicAdd(&qn[wave], 1);
                                if (pos < QW)
                                    qbuf[wave][pos] = (rowloc << 11) | (col0 + ct * 16 + m);
                            }
                    }
                }
        }
    }

    // final drain + merge
    {
        int hi = qn[wave]; if (hi > QW) hi = QW;
        drainq(qbuf[wave], hi, lane, cn, en, b, row0, bestw[wave]);
    }
    __syncthreads();
    if (tid < 64) {
        unsigned long long bb = bestw[0][tid];
        #pragma unroll
        for (int w = 1; w < 8; ++w) { unsigned long long t2 = bestw[w][tid]; if (t2 > bb) bb = t2; }
        finalidx[b * L_ + row0 + tid] = 2047 - (int)(bb & 0x7FFULL);
    }
}

// ---------------- K3: g[r] = relu(X[r]@W1+b1)@W2 + b2, fp32, BM=128 8x8 ----------------
__global__ __launch_bounds__(256) void k_feval(
        const float* __restrict__ X,
        const float* __restrict__ W1, const float* __restrict__ b1,
        const float* __restrict__ W2, const float* __restrict__ b2,
        float* __restrict__ g) {
    __shared__ __align__(16) float As[32][132];
    __shared__ __align__(16) float Bs[32][132];
    __shared__ float redv[128][16];

    int tid = threadIdx.x;
    int tx = tid & 15, ty = tid >> 4;
    int r  = tid >> 3, kg = tid & 7;
    int row0 = blockIdx.x * 128;
    const float* Ab = X + (size_t)row0 * D_;

    float acc[8][8];
    #pragma unroll
    for (int i = 0; i < 8; ++i)
        #pragma unroll
        for (int j = 0; j < 8; ++j) acc[i][j] = 0.0f;

    for (int kc = 0; kc < 4; ++kc) {
        __syncthreads();
        #pragma unroll
        for (int p = 0; p < 4; ++p) {
            int rr = r + 32 * p;
            float4 v = *(const float4*)(Ab + (size_t)rr * D_ + kc * 32 + kg * 4);
            As[kg][rr]      = v.x;
            As[8 + kg][rr]  = v.y;
            As[16 + kg][rr] = v.z;
            As[24 + kg][rr] = v.w;
        }
        {
            int kr = r, phys = (kr & 3) * 8 + (kr >> 2);
            const float* srcp = W1 + (size_t)(kc * 32 + kr) * D_ + kg * 16;
            #pragma unroll
            for (int qq = 0; qq < 4; ++qq)
                *(float4*)&Bs[phys][kg * 16 + qq * 4] = *(const float4*)(srcp + qq * 4);
        }
        __syncthreads();
        #pragma unroll
        for (int k = 0; k < 32; ++k) {
            float a[8], bb[8];
            *(float4*)&a[0]  = *(const float4*)&As[k][ty * 4];
            *(float4*)&a[4]  = *(const float4*)&As[k][64 + ty * 4];
            *(float4*)&bb[0] = *(const float4*)&Bs[k][tx * 4];
            *(float4*)&bb[4] = *(const float4*)&Bs[k][64 + tx * 4];
            #pragma unroll
            for (int i = 0; i < 8; ++i)
                #pragma unroll
                for (int j = 0; j < 8; ++j)
                    acc[i][j] = fmaf(a[i], bb[j], acc[i][j]);
        }
    }

    float w2j[8], b1j[8];
    #pragma unroll
    for (int jj = 0; jj < 8; ++jj) {
        int c = (jj < 4) ? (tx * 4 + jj) : (64 + tx * 4 + (jj - 4));
        w2j[jj] = W2[c];
        b1j[jj] = b1[c];
    }
    float bias2 = b2[0];
    __syncthreads();
    #pragma unroll
    for (int i = 0; i < 8; ++i) {
        float s = 0.0f;
        #pragma unroll
        for (int jj = 0; jj < 8; ++jj)
            s += fmaxf(acc[i][jj] + b1j[jj], 0.0f) * w2j[jj];
        int rowl = (i < 4) ? (ty * 4 + i) : (64 + ty * 4 + (i - 4));
        redv[rowl][tx] = s;
    }
    __syncthreads();
    if (tid < 128) {
        float s = 0.0f;
        #pragma unroll
        for (int tt = 0; tt < 16; ++tt) s += redv[tid][tt];
        g[row0 + tid] = s + bias2;
    }
}

// ---------------- K4: output ----------------
__global__ void k_out(const int* __restrict__ finalidx,
                      const float* __restrict__ g, float* __restrict__ out) {
    int rr = blockIdx.x * 256 + threadIdx.x;
    if (rr >= BL_) return;
    int b = rr >> 11;
    out[rr] = g[rr] + g[BL_ + (b << 11) + finalidx[rr]];
}

extern "C" void kernel_launch(void* const* d_in, const int* in_sizes, int n_in,
                              void* d_out, int out_size, void* d_ws, size_t ws_size,
                              hipStream_t stream) {
    const float* context = (const float*)d_in[0];
    const float* W1 = (const float*)d_in[1];
    const float* b1 = (const float*)d_in[2];
    const float* W2 = (const float*)d_in[3];
    const float* b2 = (const float*)d_in[4];
    float* out = (float*)d_out;

    char* ws = (char*)d_ws;
    float*  cn  = (float*)(ws);                  // 8 MB
    float*  en  = (float*)(ws + 8388608);        // 8 MB
    ushort* cnb = (ushort*)(ws + 16777216);      // 4 MB
    ushort* enb = (ushort*)(ws + 20971520);      // 4 MB
    float*  g   = (float*)(ws + 25165824);       // 128 KB
    int* finalidx = (int*)(ws + 25296896);       // 64 KB

    k_norm<<<8192, 256, 0, stream>>>(context, cn, en, cnb, enb);
    k_sim<<<256, 512, 0, stream>>>(cnb, enb, cn, en, finalidx);
    k_feval<<<256, 256, 0, stream>>>(cn, W1, b1, W2, b2, g);
    k_out<<<BL_ / 256, 256, 0, stream>>>(finalidx, g, out);
}